// Round 1
// baseline (497.634 us; speedup 1.0000x reference)
//
#include <hip/hip_runtime.h>
#include <hip/hip_bf16.h>

// The reference computes `features` and `z` but deletes them; the returned
// tensor is x.reshape(b,64,8,6,6).reshape(b,512,6,6) == x. The entire op is
// the identity on x. Kernel = device-to-device copy of 4096*512*6*6 fp32.

extern "C" void kernel_launch(void* const* d_in, const int* in_sizes, int n_in,
                              void* d_out, int out_size, void* d_ws, size_t ws_size,
                              hipStream_t stream) {
    (void)in_sizes; (void)n_in; (void)d_ws; (void)ws_size;
    const void* x = d_in[0];
    hipMemcpyAsync(d_out, x, (size_t)out_size * sizeof(float),
                   hipMemcpyDeviceToDevice, stream);
}

// Round 2
// 481.732 us; speedup vs baseline: 1.0330x; 1.0330x over previous
//
#include <hip/hip_runtime.h>
#include <hip/hip_bf16.h>

// The reference computes `features` and `z` but deletes them; the returned
// tensor is x.reshape(b,64,8,6,6).reshape(b,512,6,6) == x. The entire op is
// the identity on x. Kernel = device-to-device copy of 4096*512*6*6 fp32.
//
// hipMemcpyAsync D2D measured 1.2 TB/s under graph replay (SDMA/blit path).
// Hand-written float4 copy kernel targets the ~6.3 TB/s compute-engine
// ceiling (the harness's own fillBuffer kernels hit 6.4-6.5 TB/s).

__global__ __launch_bounds__(256) void copy_f4(const float4* __restrict__ src,
                                               float4* __restrict__ dst,
                                               int n4) {
    int i = blockIdx.x * 256 + threadIdx.x;
    if (i < n4) dst[i] = src[i];
}

extern "C" void kernel_launch(void* const* d_in, const int* in_sizes, int n_in,
                              void* d_out, int out_size, void* d_ws, size_t ws_size,
                              hipStream_t stream) {
    (void)in_sizes; (void)n_in; (void)d_ws; (void)ws_size;
    const float4* x = (const float4*)d_in[0];
    float4* out = (float4*)d_out;
    int n4 = out_size / 4;             // 75,497,472 / 4 = 18,874,368 float4s
    int blocks = (n4 + 255) / 256;     // 73,728 blocks
    copy_f4<<<blocks, 256, 0, stream>>>(x, out, n4);
}